// Round 4
// baseline (69.889 us; speedup 1.0000x reference)
//
#include <hip/hip_runtime.h>

// IDWT3D (Haar, stride-2 transposed conv, groups=C):
// out[b,c,2d+i,2h+j,2w+k] = sum_s y[b,c,s,d,h,w] * K[s,i,j,k]
// y = concat(low, highs) over s (s=0 -> low, s=1..7 -> highs).
//
// Shapes: low [2,32,48,48,48] f32, highs [2,32,7,48,48,48] f32,
//         K [8,2,2,2] f32, out [2,32,96,96,96] f32.
//
// R3 result: 68.7 us @ 454 MB moved (6.6 TB/s effective; HBM side ~340 MB
// since inputs half-hit L3). R4: double per-thread MLP — each thread runs two
// independent dense pipelines (idx and idx+NT/2) to double in-flight bytes.
// All loads remain dense float2 (8 B/lane), all stores dense nontemporal
// float4 (16 B/lane).

typedef float f32x4 __attribute__((ext_vector_type(4)));
typedef float f32x2 __attribute__((ext_vector_type(2)));

constexpr int Bn = 2, Cn = 32, Dn = 48, Hn = 48, Wn = 48;
constexpr int WPT = 2;               // coarse w voxels per pipeline
constexpr int WQ  = Wn / WPT;        // 24
constexpr int NT  = Bn * Cn * Dn * Hn * WQ;  // 3,538,944 pipeline instances
constexpr int SUBBAND_STRIDE = Dn * Hn * Wn; // 110,592
constexpr int PIPES = 2;             // pipelines per thread
constexpr int NTH  = NT / PIPES;     // 1,769,472 threads

__device__ __forceinline__ void run_pipe(
    int idx, const float* __restrict__ low, const float* __restrict__ highs,
    const float* __restrict__ sk, float* __restrict__ out)
{
    int wq = idx % WQ;
    int t  = idx / WQ;
    int h  = t % Hn; t /= Hn;
    int d  = t % Dn; t /= Dn;
    int bc = t;                      // b*C + c  (0..63)
    int w0 = wq * WPT;

    // ---- load 8 subband values for 2 consecutive w (dense float2 loads) ----
    float y[8][2];
    int cvox = ((bc * Dn + d) * Hn + h) * Wn + w0;
    f32x2 v = *reinterpret_cast<const f32x2*>(low + cvox);
    y[0][0] = v.x; y[0][1] = v.y;

    int hbase = ((bc * 7 * Dn + d) * Hn + h) * Wn + w0;
#pragma unroll
    for (int s = 0; s < 7; ++s) {
        f32x2 u = *reinterpret_cast<const f32x2*>(highs + hbase + s * SUBBAND_STRIDE);
        y[s + 1][0] = u.x; y[s + 1][1] = u.y;
    }

    // ---- compute + store: 4 output rows (i,j), one dense 16B nt store each ----
    const int D2 = 2 * Dn, H2 = 2 * Hn, W2 = 2 * Wn;
    const int od = 2 * d, oh = 2 * h, ow = 2 * w0;

#pragma unroll
    for (int i = 0; i < 2; ++i) {
#pragma unroll
        for (int j = 0; j < 2; ++j) {
            float k0[8], k1[8];
#pragma unroll
            for (int s = 0; s < 8; ++s) {
                k0[s] = sk[s * 8 + i * 4 + j * 2 + 0];
                k1[s] = sk[s * 8 + i * 4 + j * 2 + 1];
            }

            f32x4 o;
#pragma unroll
            for (int wsub = 0; wsub < 2; ++wsub) {
                float a0 = 0.f, a1 = 0.f;
#pragma unroll
                for (int s = 0; s < 8; ++s) {
                    a0 = fmaf(y[s][wsub], k0[s], a0);
                    a1 = fmaf(y[s][wsub], k1[s], a1);
                }
                o[2 * wsub + 0] = a0;
                o[2 * wsub + 1] = a1;
            }

            int obase = ((bc * D2 + (od + i)) * H2 + (oh + j)) * W2 + ow;
            __builtin_nontemporal_store(o, reinterpret_cast<f32x4*>(out + obase));
        }
    }
}

__global__ __launch_bounds__(256) void idwt3d_kernel(
    const float* __restrict__ low,
    const float* __restrict__ highs,
    const float* __restrict__ ker,
    float* __restrict__ out)
{
    __shared__ float sk[64];
    if (threadIdx.x < 64) sk[threadIdx.x] = ker[threadIdx.x];
    __syncthreads();

    int idx = blockIdx.x * 256 + threadIdx.x;
    // Two independent dense pipelines per thread -> 2x in-flight bytes.
    run_pipe(idx,       low, highs, sk, out);
    run_pipe(idx + NTH, low, highs, sk, out);
}

extern "C" void kernel_launch(void* const* d_in, const int* in_sizes, int n_in,
                              void* d_out, int out_size, void* d_ws, size_t ws_size,
                              hipStream_t stream) {
    const float* low   = (const float*)d_in[0];
    const float* highs = (const float*)d_in[1];
    const float* ker   = (const float*)d_in[2];
    float* out = (float*)d_out;

    constexpr int BLK = 256;
    constexpr int GRID = NTH / BLK;  // 6912, exact cover
    idwt3d_kernel<<<GRID, BLK, 0, stream>>>(low, highs, ker, out);
}

// Round 5
// 68.894 us; speedup vs baseline: 1.0144x; 1.0144x over previous
//
#include <hip/hip_runtime.h>

// IDWT3D (Haar, stride-2 transposed conv, groups=C):
// out[b,c,2d+i,2h+j,2w+k] = sum_s y[b,c,s,d,h,w] * K[s,i,j,k]
// y = concat(low, highs) over s (s=0 -> low, s=1..7 -> highs).
//
// Shapes: low [2,32,48,48,48] f32, highs [2,32,7,48,48,48] f32,
//         K [8,2,2,2] f32, out [2,32,96,96,96] f32.
//
// FINAL (R3 variant, 68.7 us): memory-bound streaming op at saturation.
//   - traffic is exactly ideal: 227 MB read (113 MB from HBM, rest L3-hit),
//     226.5 MB written; 454 MB effective / 68.7 us = 6.6 TB/s, above the
//     6.29 TB/s pure-HBM copy ceiling thanks to L3 read hits.
//   - R4's 2x per-thread MLP experiment was neutral -> not latency-limited.
//   - WPT=2: loads dense float2 (8 B/lane), stores one dense nontemporal
//     float4 (16 B/lane) per output row; k-interleave of the 2x upsample
//     makes output rows contiguous. Kernel bank in LDS (broadcast reads).

typedef float f32x4 __attribute__((ext_vector_type(4)));
typedef float f32x2 __attribute__((ext_vector_type(2)));

constexpr int Bn = 2, Cn = 32, Dn = 48, Hn = 48, Wn = 48;
constexpr int WPT = 2;               // coarse w voxels per thread
constexpr int WQ  = Wn / WPT;        // 24
constexpr int NT  = Bn * Cn * Dn * Hn * WQ;  // 3,538,944 threads
constexpr int SUBBAND_STRIDE = Dn * Hn * Wn; // 110,592

__global__ __launch_bounds__(256) void idwt3d_kernel(
    const float* __restrict__ low,
    const float* __restrict__ highs,
    const float* __restrict__ ker,
    float* __restrict__ out)
{
    __shared__ float sk[64];
    if (threadIdx.x < 64) sk[threadIdx.x] = ker[threadIdx.x];
    __syncthreads();

    int idx = blockIdx.x * 256 + threadIdx.x;
    if (idx >= NT) return;

    int wq = idx % WQ;
    int t  = idx / WQ;
    int h  = t % Hn; t /= Hn;
    int d  = t % Dn; t /= Dn;
    int bc = t;                      // b*C + c  (0..63)
    int w0 = wq * WPT;

    // ---- load 8 subband values for 2 consecutive w (dense float2 loads) ----
    float y[8][2];
    {
        int cvox = ((bc * Dn + d) * Hn + h) * Wn + w0;
        f32x2 v = *reinterpret_cast<const f32x2*>(low + cvox);
        y[0][0] = v.x; y[0][1] = v.y;

        int hbase = ((bc * 7 * Dn + d) * Hn + h) * Wn + w0;
#pragma unroll
        for (int s = 0; s < 7; ++s) {
            f32x2 u = *reinterpret_cast<const f32x2*>(highs + hbase + s * SUBBAND_STRIDE);
            y[s + 1][0] = u.x; y[s + 1][1] = u.y;
        }
    }

    // ---- compute + store: 4 output rows (i,j), one dense 16B nt store each ----
    const int D2 = 2 * Dn, H2 = 2 * Hn, W2 = 2 * Wn;
    const int od = 2 * d, oh = 2 * h, ow = 2 * w0;

#pragma unroll
    for (int i = 0; i < 2; ++i) {
#pragma unroll
        for (int j = 0; j < 2; ++j) {
            float k0[8], k1[8];
#pragma unroll
            for (int s = 0; s < 8; ++s) {
                k0[s] = sk[s * 8 + i * 4 + j * 2 + 0];
                k1[s] = sk[s * 8 + i * 4 + j * 2 + 1];
            }

            f32x4 o;
#pragma unroll
            for (int wsub = 0; wsub < 2; ++wsub) {
                float a0 = 0.f, a1 = 0.f;
#pragma unroll
                for (int s = 0; s < 8; ++s) {
                    a0 = fmaf(y[s][wsub], k0[s], a0);
                    a1 = fmaf(y[s][wsub], k1[s], a1);
                }
                o[2 * wsub + 0] = a0;
                o[2 * wsub + 1] = a1;
            }

            int obase = ((bc * D2 + (od + i)) * H2 + (oh + j)) * W2 + ow;
            __builtin_nontemporal_store(o, reinterpret_cast<f32x4*>(out + obase));
        }
    }
}

extern "C" void kernel_launch(void* const* d_in, const int* in_sizes, int n_in,
                              void* d_out, int out_size, void* d_ws, size_t ws_size,
                              hipStream_t stream) {
    const float* low   = (const float*)d_in[0];
    const float* highs = (const float*)d_in[1];
    const float* ker   = (const float*)d_in[2];
    float* out = (float*)d_out;

    constexpr int BLK = 256;
    constexpr int GRID = NT / BLK;   // 13824, exact cover
    idwt3d_kernel<<<GRID, BLK, 0, stream>>>(low, highs, ker, out);
}